// Round 3
// baseline (45.476 us; speedup 1.0000x reference)
//
#include <hip/hip_runtime.h>
#include <hip/hip_bf16.h>

#define RES_   2048
#define CH_    128          // steps per chunk
#define NCH    512          // 65536 / CH_
#define TS_    32           // output tile side (px)
#define KPAD   136          // 128 + 8 halfs: row stride 272B, 16B-aligned
#define NTHR   512          // 8 waves: 4 subtiles x 2 K-halves

typedef _Float16 half8  __attribute__((ext_vector_type(8)));
typedef float   float2_ __attribute__((ext_vector_type(2)));
typedef float   float4_ __attribute__((ext_vector_type(4)));

// Exact reference float32 math (verbatim from R1/R2 — bit-exact floor decisions).
__device__ __forceinline__ void step_eval(int gs, float p0x, float p0y, float p1x, float p1y,
                                          float p2x, float p2y, float& cx, float& cy) {
    const float tl = (float)((double)gs / 65535.0);      // linspace(0,1,STEPS)
    const float to = (float)gs * (1.0f / 65536.0f);      // arange(STEPS)/STEPS (exact)
    const float ax  = __fadd_rn(p0x, __fmul_rn(__fsub_rn(p1x, p0x), tl));
    const float ay  = __fadd_rn(p0y, __fmul_rn(__fsub_rn(p1y, p0y), tl));
    const float bxf = __fadd_rn(p1x, __fmul_rn(__fsub_rn(p2x, p1x), tl));
    const float byf = __fadd_rn(p1y, __fmul_rn(__fsub_rn(p2y, p1y), tl));
    cx = __fadd_rn(ax, __fmul_rn(to, __fsub_rn(bxf, ax)));
    cy = __fadd_rn(ay, __fmul_rn(to, __fsub_rn(byf, ay)));
}

// Cheap f32 eval for prologue bboxes only (error ~4e-4 px, covered by 2px margin).
__device__ __forceinline__ void step_eval_fast(int gs, float p0x, float p0y, float p1x, float p1y,
                                               float p2x, float p2y, float& cx, float& cy) {
    const float tl = (float)gs * (1.0f / 65535.0f);
    const float to = (float)gs * (1.0f / 65536.0f);
    const float ax  = p0x + (p1x - p0x) * tl;
    const float ay  = p0y + (p1y - p0y) * tl;
    const float bxf = p1x + (p2x - p1x) * tl;
    const float byf = p1y + (p2y - p1y) * tl;
    cx = ax + to * (bxf - ax);
    cy = ay + to * (byf - ay);
}

__global__ __launch_bounds__(NTHR) void bezier_tiles(const float* __restrict__ cp,
                                                     float* __restrict__ out) {
    __shared__ _Float16 sExT[TS_][KPAD];   // [tile_row][step] masked exp_x
    __shared__ _Float16 sEyT[TS_][KPAD];   // [tile_col][step] masked exp_y
    __shared__ float    sOut[TS_][36];     // f32 tile staging (pad 36 words)
    __shared__ float    s_cx[CH_], s_cy[CH_];
    __shared__ int      s_bx[CH_], s_by[CH_];
    __shared__ unsigned short s_list[NCH];
    __shared__ int      s_wcnt[8];
    __shared__ int      s_count;

    const int tid = threadIdx.x;
    const int bid = blockIdx.x;
    const int Tx = (bid >> 6) * TS_;       // tile row origin (gx)
    const int Ty = (bid & 63) * TS_;       // tile col origin (gy)

    const float p0x = cp[0], p0y = cp[1], p1x = cp[2], p1y = cp[3], p2x = cp[4], p2y = cp[5];

    // ---- Prologue: per-chunk stamp bbox (analytic, 2px margin) + overlap list ----
    bool ov = false;
    {
        float x0, y0, x1, y1;
        step_eval_fast(tid * CH_,           p0x,p0y,p1x,p1y,p2x,p2y, x0, y0);
        step_eval_fast(tid * CH_ + CH_ - 1, p0x,p0y,p1x,p1y,p2x,p2y, x1, y1);
        // block-corner range (floor+clamp are monotone; +-2px margin pre-clamp)
        const int bxlo = min(max((int)floorf(2048.f * fminf(x0, x1)) - 18, 0), RES_ - 32);
        const int bxhi = min(max((int)floorf(2048.f * fmaxf(x0, x1)) - 14, 0), RES_ - 32);
        const int bylo = min(max((int)floorf(2048.f * fminf(y0, y1)) - 18, 0), RES_ - 32);
        const int byhi = min(max((int)floorf(2048.f * fmaxf(y0, y1)) - 14, 0), RES_ - 32);
        // stamp pixels: rows [bxlo, bxhi+31], cols [bylo, byhi+31]; tile [Tx,Tx+31]x[Ty,Ty+31]
        ov = (bxlo <= Tx + TS_ - 1) && (bxhi + 31 >= Tx) &&
             (bylo <= Ty + TS_ - 1) && (byhi + 31 >= Ty);
    }
    const unsigned long long m = __ballot(ov ? 1 : 0);
    const int lane = tid & 63;
    const int w    = tid >> 6;
    if (lane == 0) s_wcnt[w] = __popcll(m);
    __syncthreads();
    if (ov) {
        int pre = 0;
        for (int i = 0; i < w; ++i) pre += s_wcnt[i];
        const int pos = pre + __popcll(m & ((1ull << lane) - 1ull));
        s_list[pos] = (unsigned short)tid;    // ascending chunk order -> deterministic
    }
    if (tid == 0) {
        int t = 0;
        for (int i = 0; i < 8; ++i) t += s_wcnt[i];
        s_count = t;
    }
    __syncthreads();
    const int cnt = s_count;

    const int orow = tid >> 4;              // 0..31
    const int oc2  = (tid & 15) * 2;        // 0..30
    float* const orow_ptr = &out[(size_t)(Tx + orow) * RES_ + Ty + oc2];

    if (cnt == 0) {                         // fast path: pure zero tile
        *(float2_*)orow_ptr = float2_{0.f, 0.f};
        return;
    }

    // ---- Pair loop: accumulate tile = sum over chunks of Ex^T * Ey ----
    const int st = w & 3;                   // subtile 0..3
    const int kh = w >> 2;                  // K-half 0..1
    const int mt = st >> 1, nt = st & 1;
    const int arow = mt * 16 + (lane & 15);
    const int bcol = nt * 16 + (lane & 15);
    const int kg   = kh * 64 + (lane >> 4) * 8;
    float4_ acc = {0.f, 0.f, 0.f, 0.f};

    for (int p = 0; p < cnt; ++p) {
        const int c = s_list[p];
        // Phase A: exact per-step curve pos + clamped block corner
        if (tid < CH_) {
            float cx, cy;
            step_eval(c * CH_ + tid, p0x,p0y,p1x,p1y,p2x,p2y, cx, cy);
            s_cx[tid] = cx; s_cy[tid] = cy;
            s_bx[tid] = min(max((int)floorf(__fmul_rn(2048.0f, cx)) - 16, 0), RES_ - 32);
            s_by[tid] = min(max((int)floorf(__fmul_rn(2048.0f, cy)) - 16, 0), RES_ - 32);
        }
        __syncthreads();
        // Phase B: masked transposed f16 exp tables (2 tables x 32 cols x 16 grp = 1024 items)
        #pragma unroll
        for (int rep = 0; rep < 2; ++rep) {
            const int it    = tid + rep * NTHR;
            const int table = it >> 9;
            const int rem   = it & 511;
            const int o     = rem >> 4;          // 0..31
            const int s0    = (rem & 15) * 8;
            const float* cc = table ? s_cy : s_cx;
            const int*   bb = table ? s_by : s_bx;
            const int  base = table ? Ty : Tx;
            const float ci  = (float)(base + o) * (1.0f / 2048.0f);
            half8 v;
            #pragma unroll
            for (int j = 0; j < 8; ++j) {
                const int s = s0 + j;
                const float d = __fsub_rn(cc[s], ci);
                const float e = __expf(-__fmul_rn(__fmul_rn(d, d), 5000.0f));
                const unsigned orel = (unsigned)(base + o - bb[s]);
                v[j] = (orel < 32u) ? (_Float16)e : (_Float16)0.0f;
            }
            *(half8*)(table ? &sEyT[o][s0] : &sExT[o][s0]) = v;
        }
        __syncthreads();
        // Phase C: per wave, one 16x16 subtile x one K-half (2 MFMAs)
        #pragma unroll
        for (int kb = 0; kb < 2; ++kb) {
            const int k = kb * 32 + kg;
            const half8 aF = *(const half8*)&sExT[arow][k];
            const half8 bF = *(const half8*)&sEyT[bcol][k];
            acc = __builtin_amdgcn_mfma_f32_16x16x32_f16(aF, bF, acc, 0, 0, 0);
        }
        __syncthreads();   // protect tables/step data for next pair
    }

    // ---- Flush: merge K-halves through LDS, then one coalesced write ----
    const float sc = 1.0f / 65536.0f;      // /STEPS (exact pow2)
    const int coll = lane & 15;
    const int rowb = (lane >> 4) * 4;
    if (kh == 0) {
        #pragma unroll
        for (int r = 0; r < 4; ++r)
            sOut[mt * 16 + rowb + r][nt * 16 + coll] = acc[r] * sc;
    }
    __syncthreads();
    if (kh == 1) {
        #pragma unroll
        for (int r = 0; r < 4; ++r)
            sOut[mt * 16 + rowb + r][nt * 16 + coll] += acc[r] * sc;
    }
    __syncthreads();
    *(float2_*)orow_ptr = *(const float2_*)&sOut[orow][oc2];
}

extern "C" void kernel_launch(void* const* d_in, const int* in_sizes, int n_in,
                              void* d_out, int out_size, void* d_ws, size_t ws_size,
                              hipStream_t stream) {
    const float* cp = (const float*)d_in[0];
    float* out = (float*)d_out;
    // Single kernel: 64x64 tiles of 32x32 px; full-coverage non-atomic writes (no memset).
    hipLaunchKernelGGL(bezier_tiles, dim3(4096), dim3(NTHR), 0, stream, cp, out);
}

// Round 4
// 21.206 us; speedup vs baseline: 2.1445x; 2.1445x over previous
//
#include <hip/hip_runtime.h>
#include <hip/hip_bf16.h>

#define RES_    2048
#define CSTEPS  128     // steps per workgroup
#define TILE_   48      // span <= 8px movement + 32 window = 40 <= 48 (3x3 MFMA tiles)
#define KPAD    136     // 128 + 8 halfs pad: row stride 272B, 16B-aligned
#define NTHR    576     // 9 waves: one 16x16 output tile each

typedef _Float16 half8 __attribute__((ext_vector_type(8)));
typedef float   float4_ __attribute__((ext_vector_type(4)));

__global__ __launch_bounds__(1024) void zero_out(float4_* __restrict__ out) {
    out[(size_t)blockIdx.x * 1024 + threadIdx.x] = float4_{0.f, 0.f, 0.f, 0.f};
}

__global__ __launch_bounds__(NTHR) void bezier_scatter(const float* __restrict__ cp,
                                                       float* __restrict__ out) {
    __shared__ _Float16 sExT[TILE_][KPAD];   // [col_offset][step], masked exp_x
    __shared__ _Float16 sEyT[TILE_][KPAD];   // [col_offset][step], masked exp_y
    __shared__ float s_cx[CSTEPS], s_cy[CSTEPS];
    __shared__ int   s_bx[CSTEPS], s_by[CSTEPS];
    __shared__ int   s_Ax, s_Ay;

    const int tid = threadIdx.x;

    // ---- Phase A: per-step curve position & block corner (exact ref float32 math) ----
    if (tid < CSTEPS) {
        const int gs = blockIdx.x * CSTEPS + tid;
        const float tl = (float)((double)gs / 65535.0);      // linspace(0,1,STEPS)
        const float to = (float)gs * (1.0f / 65536.0f);      // arange(STEPS)/STEPS (exact)
        const float p0x = cp[0], p0y = cp[1], p1x = cp[2], p1y = cp[3], p2x = cp[4], p2y = cp[5];
        const float ax = __fadd_rn(p0x, __fmul_rn(__fsub_rn(p1x, p0x), tl));
        const float ay = __fadd_rn(p0y, __fmul_rn(__fsub_rn(p1y, p0y), tl));
        const float bxf = __fadd_rn(p1x, __fmul_rn(__fsub_rn(p2x, p1x), tl));
        const float byf = __fadd_rn(p1y, __fmul_rn(__fsub_rn(p2y, p1y), tl));
        const float cx = __fadd_rn(ax, __fmul_rn(to, __fsub_rn(bxf, ax)));
        const float cy = __fadd_rn(ay, __fmul_rn(to, __fsub_rn(byf, ay)));
        const int bxi = min(max((int)floorf(__fmul_rn(2048.0f, cx)) - 16, 0), RES_ - 32);
        const int byi = min(max((int)floorf(__fmul_rn(2048.0f, cy)) - 16, 0), RES_ - 32);
        s_cx[tid] = cx; s_cy[tid] = cy; s_bx[tid] = bxi; s_by[tid] = byi;
        if (tid == 0) {
            // |bx_s - bx_0| <= 8 over 128 steps -> windows subset of [bx0-8, bx0+40) (48 wide)
            s_Ax = min(max(bxi - 8, 0), RES_ - TILE_);
            s_Ay = min(max(byi - 8, 0), RES_ - TILE_);
        }
    }
    __syncthreads();
    const int Ax = s_Ax, Ay = s_Ay;

    // ---- Phase B: fill masked transposed f16 exp tables ----
    // 2 tables * 48 cols * 16 step-groups(8) = 1536 items over 576 threads
    for (int it = tid; it < 2 * TILE_ * (CSTEPS / 8); it += NTHR) {
        const int half_ = TILE_ * (CSTEPS / 8);       // 768
        const int table = (it >= half_);
        const int rem   = it - table * half_;
        const int o     = rem >> 4;                   // tile col offset 0..47
        const int s0    = (rem & 15) * 8;             // step group start
        const float* cc = table ? s_cy : s_cx;
        const int*   bb = table ? s_by : s_bx;
        const int  base = table ? s_Ay : s_Ax;
        const float ci  = (float)(base + o) * (1.0f / 2048.0f);   // exact (pow2 div)
        half8 v;
        #pragma unroll
        for (int j = 0; j < 8; ++j) {
            const int s = s0 + j;
            const float d = __fsub_rn(cc[s], ci);
            const float e = __expf(-__fmul_rn(__fmul_rn(d, d), 5000.0f));
            const unsigned orel = (unsigned)(base + o - bb[s]);
            v[j] = (orel < 32u) ? (_Float16)e : (_Float16)0.0f;
        }
        *(half8*)(table ? &sEyT[o][s0] : &sExT[o][s0]) = v;
    }
    __syncthreads();

    // ---- Phase C: 48x48 tile = Ex^T (48x128) * Ey (128x48); 9 waves, 1 tile each ----
    const int lane = tid & 63;
    const int wid  = tid >> 6;          // 0..8
    const int mt   = wid / 3, nt = wid - mt * 3;
    const int arow = mt * 16 + (lane & 15);
    const int bcol = nt * 16 + (lane & 15);
    const int kgrp = (lane >> 4) * 8;
    float4_ acc = {0.f, 0.f, 0.f, 0.f};
    #pragma unroll
    for (int kb = 0; kb < CSTEPS / 32; ++kb) {
        const half8 aF = *(const half8*)&sExT[arow][kb * 32 + kgrp];
        const half8 bF = *(const half8*)&sEyT[bcol][kb * 32 + kgrp];
        acc = __builtin_amdgcn_mfma_f32_16x16x32_f16(aF, bF, acc, 0, 0, 0);
    }

    // ---- Flush: C/D layout col = lane&15, row = (lane>>4)*4 + reg (confirmed R1) ----
    const int coll = lane & 15;
    const int rowb = (lane >> 4) * 4;
    #pragma unroll
    for (int r = 0; r < 4; ++r) {
        const float v = acc[r];
        if (v != 0.0f) {   // nonzero only inside valid clamped windows
            const int gx = Ax + mt * 16 + rowb + r;
            const int gy = Ay + nt * 16 + coll;
            atomicAdd(&out[gx * RES_ + gy], v * (1.0f / 65536.0f));  // /STEPS exact (pow2)
        }
    }
}

extern "C" void kernel_launch(void* const* d_in, const int* in_sizes, int n_in,
                              void* d_out, int out_size, void* d_ws, size_t ws_size,
                              hipStream_t stream) {
    const float* cp = (const float*)d_in[0];
    float* out = (float*)d_out;
    // Custom zero kernel (A/B vs graph memset node): 1024x1024 float4 = 16.78 MB
    hipLaunchKernelGGL(zero_out, dim3(1024), dim3(1024), 0, stream, (float4_*)out);
    // 512 WGs x 128 steps each (2 WGs/CU)
    hipLaunchKernelGGL(bezier_scatter, dim3(65536 / CSTEPS), dim3(NTHR), 0, stream, cp, out);
}